// Round 1
// baseline (354.124 us; speedup 1.0000x reference)
//
#include <hip/hip_runtime.h>
#include <hip/hip_bf16.h>
#include <hip/hip_fp16.h>
#include <math.h>

// SGC: out = log_softmax( S^2 X W^T + b ), S = D^-1/2 (A+I) D^-1/2
// t0 = dis .* (X W^T) in *f16* (pre-scaled 80 B rows).
// Propagation: one 5-lane GROUP per dst node (12 nodes/wave). Lane sl owns
// bytes [16*sl, 16*sl+16) of the row; f32 accumulation (shorter rounding
// chain than f16), no cross-lane folds needed. Softmax via 4 rotate-shfls
// within the 5-lane group.
// CSR via two-level bucketed counting sort with power-of-2 bucket ranges.

#define N_NODES 100000
#define N_FEAT  128
#define N_CLASS 40

#define RANGE   256           // dsts per fine bucket (pow2: dst>>8)
#define NBALLOC 512
#define NBUSED  391           // ceil(100000/256)
#define RANGE_C 2048          // dsts per coarse bucket (dst>>11)
#define NCALLOC 64
#define NCUSED  49            // ceil(100000/2048)
#define CAP     8704          // fine bucket LDS cap (mean 8192 + ~5.7 sigma)
#define CCAP    67072         // coarse region cap (mean 65536 + ~6 sigma)
#define P3AGRID 1024

typedef __attribute__((ext_vector_type(8))) short short8;   // 8 bf16 (4 VGPRs)
typedef __attribute__((ext_vector_type(4))) float floatx4;  // MFMA C/D

// ---------------------------------------------------------------------------
// Detect int32 vs int64 edge_index words; zero counters. 1 block x 512.
__global__ void detect_zero_kernel(const int* __restrict__ ei, int* __restrict__ flag,
                                   int* __restrict__ bucketCount,
                                   int* __restrict__ coarseCnt) {
    int t = threadIdx.x;
    if (t < NBALLOC) bucketCount[t] = 0;
    if (t < NCALLOC) coarseCnt[t] = 0;
    if (t < 64) {
        int nz = (ei[2 * t + 1] != 0) ? 1 : 0;
        unsigned long long b = __ballot(nz);
        if (t == 0) *flag = (b == 0ull) ? 1 : 0;   // 1 => int64 layout
    }
}

__device__ __forceinline__ int edge_word(const int* ei, int elem, int is64) {
    return is64 ? ei[2 * elem] : ei[elem];
}

// P3a: scatter packed records (dstLocalCoarse<<17 | src) into per-block dense
// runs within coarse regions; simultaneously build the fine histogram.
__global__ __launch_bounds__(256) void p3a_scatter(
    const int* __restrict__ ei, int E, const int* __restrict__ flag,
    int* __restrict__ bucketCount, int* __restrict__ coarseCnt,
    unsigned int* __restrict__ tmpc)
{
    __shared__ int hf[NBALLOC];
    __shared__ int hc[NCALLOC];
    __shared__ int basec[NCALLOC];
    __shared__ int curc[NCALLOC];
    int t = threadIdx.x;
    for (int i = t; i < NBALLOC; i += 256) hf[i] = 0;
    if (t < NCALLOC) hc[t] = 0;
    __syncthreads();
    int is64 = *flag;
    int per = (E + gridDim.x - 1) / gridDim.x;
    int e0 = blockIdx.x * per;
    int e1 = min(E, e0 + per);
    for (int e = e0 + t; e < e1; e += 256) {
        int c = edge_word(ei, E + e, is64);
        atomicAdd(&hf[c >> 8], 1);
        atomicAdd(&hc[c >> 11], 1);
    }
    __syncthreads();
    if (t < NCALLOC) {
        basec[t] = hc[t] ? atomicAdd(&coarseCnt[t], hc[t]) : 0;
        curc[t] = 0;
    }
    for (int i = t; i < NBALLOC; i += 256)
        if (hf[i]) atomicAdd(&bucketCount[i], hf[i]);
    __syncthreads();
    for (int e = e0 + t; e < e1; e += 256) {
        int c = edge_word(ei, E + e, is64);
        int r = edge_word(ei, e, is64);
        int cb = c >> 11;
        int p = basec[cb] + atomicAdd(&curc[cb], 1);
        if (p < CCAP)
            tmpc[(size_t)cb * CCAP + p] = ((unsigned)(c & 2047) << 17) | (unsigned)r;
    }
}

// P2: scan fine counts -> bucketStart/bucketCursor; starts[N]=E.
__global__ __launch_bounds__(NBALLOC) void p2_scan(
    const int* __restrict__ bucketCount, int* __restrict__ bucketStart,
    int* __restrict__ bucketCursor, int* __restrict__ starts, int E)
{
    __shared__ int s[NBALLOC];
    int t = threadIdx.x;
    int v = bucketCount[t];
    s[t] = v;
    __syncthreads();
    for (int o = 1; o < NBALLOC; o <<= 1) {
        int y = (t >= o) ? s[t - o] : 0;
        __syncthreads();
        s[t] += y;
        __syncthreads();
    }
    int incl = s[t], excl = incl - v;
    bucketStart[t] = excl;
    bucketCursor[t] = excl;
    if (t == NBALLOC - 1) { bucketStart[NBALLOC] = incl; starts[N_NODES] = E; }
}

// P3b: 8 blocks per coarse bucket; re-scatter into its 8 fine buckets.
__global__ __launch_bounds__(256) void p3b_scatter(
    const unsigned int* __restrict__ tmpc, const int* __restrict__ coarseCnt,
    int* __restrict__ bucketCursor, unsigned int* __restrict__ tmp)
{
    __shared__ int fh[8];
    __shared__ int fb[8];
    __shared__ int fc[8];
    int cb = blockIdx.x >> 3;
    int j = blockIdx.x & 7;
    int t = threadIdx.x;
    int cnt = coarseCnt[cb];
    if (cnt > CCAP) cnt = CCAP;
    int chunk = (cnt + 7) >> 3;
    int r0 = j * chunk;
    int r1 = min(cnt, r0 + chunk);
    if (t < 8) fh[t] = 0;
    __syncthreads();
    const unsigned int* rec = tmpc + (size_t)cb * CCAP;
    for (int i = r0 + t; i < r1; i += 256) {
        int dlc = (int)(rec[i] >> 17);
        atomicAdd(&fh[dlc >> 8], 1);
    }
    __syncthreads();
    if (t < 8) {
        fb[t] = fh[t] ? atomicAdd(&bucketCursor[cb * 8 + t], fh[t]) : 0;
        fc[t] = 0;
    }
    __syncthreads();
    for (int i = r0 + t; i < r1; i += 256) {
        unsigned v = rec[i];
        int dlc = (int)(v >> 17);
        unsigned src = v & 0x1FFFFu;
        int fi = dlc >> 8;
        int dlf = dlc & 255;
        int p = fb[fi] + atomicAdd(&fc[fi], 1);
        tmp[p] = ((unsigned)dlf << 24) | src;
    }
}

// P4: per-fine-bucket LDS counting sort -> starts, dis, srcsB (byte offsets,
// src*80, coalesced). No rec[] cache: tmp is read twice (streaming).
__global__ __launch_bounds__(256) void p4_sort(
    const unsigned int* __restrict__ tmp, const int* __restrict__ bucketStart,
    int* __restrict__ starts, float* __restrict__ dis, int* __restrict__ srcsB, int N)
{
    __shared__ int srt[CAP];
    __shared__ int hist[256];
    __shared__ int sc[256];
    __shared__ int cur[256];
    int b = blockIdx.x, t = threadIdx.x;
    int g0 = b * RANGE;
    int gcnt = N - g0;
    if (gcnt > RANGE) gcnt = RANGE;
    int base = bucketStart[b];
    int n = bucketStart[b + 1] - base;
    hist[t] = 0;
    __syncthreads();
    for (int i = t; i < n; i += 256)
        atomicAdd(&hist[tmp[base + i] >> 24], 1);
    __syncthreads();
    int hv = hist[t];
    sc[t] = hv;
    __syncthreads();
    for (int o = 1; o < 256; o <<= 1) {
        int y = (t >= o) ? sc[t - o] : 0;
        __syncthreads();
        sc[t] += y;
        __syncthreads();
    }
    int excl = sc[t] - hv;
    if (t < gcnt) {
        starts[g0 + t] = base + excl;
        dis[g0 + t] = rsqrtf((float)(hv + 1));   // +1 self-loop
    }
    cur[t] = excl;
    __syncthreads();
    if (n <= CAP) {
        for (int i = t; i < n; i += 256) {
            unsigned v = tmp[base + i];
            int p = atomicAdd(&cur[v >> 24], 1);
            srt[p] = (int)(v & 0xFFFFFFu) * 80;   // pre-scaled byte offset
        }
        __syncthreads();
        for (int i = t; i < n; i += 256) srcsB[base + i] = srt[i];
    } else {
        // overflow fallback (statistically never taken)
        for (int i = t; i < n; i += 256) {
            unsigned v = tmp[base + i];
            int p = atomicAdd(&cur[v >> 24], 1);
            srcsB[base + p] = (int)(v & 0xFFFFFFu) * 80;
        }
    }
}

// ---------------------------------------------------------------------------
__device__ __forceinline__ unsigned short f2bf(float f) {   // RTN f32 -> bf16
    unsigned u = __float_as_uint(f);
    unsigned r = u + 0x7FFFu + ((u >> 16) & 1u);
    return (unsigned short)(r >> 16);
}
__device__ __forceinline__ __half2 u2h(unsigned w) {
    union { unsigned u; __half2 h; } c; c.u = w; return c.h;
}
__device__ __forceinline__ unsigned h2u(__half2 h) {
    union { unsigned u; __half2 h; } c; c.h = h; return c.u;
}

// t0 = dis .* (X @ W^T), f16, row stride 40 (80 B). One wave per 16 nodes.
// MFMA on bf16 inputs (f32 accumulate), output stored f16.
__global__ __launch_bounds__(256) void transform_mfma(
    const float* __restrict__ x, const float* __restrict__ W,
    const float* __restrict__ dis, unsigned short* __restrict__ t0, int N)
{
    __shared__ uint4 Wl[3 * 4 * 64];        // B frags, bf16-packed: 12 KiB
    int t = threadIdx.x;
    for (int i = t; i < 3 * 4 * 64; i += 256) {
        int lane = i & 63;
        int kc = (i >> 6) & 3;
        int nt = i >> 8;
        int n = nt * 16 + (lane & 15);
        int k = kc * 32 + (lane >> 4) * 8;
        union { unsigned short s[8]; uint4 v; } u;
        #pragma unroll
        for (int j = 0; j < 8; ++j)
            u.s[j] = (n < N_CLASS) ? f2bf(W[n * N_FEAT + k + j]) : (unsigned short)0;
        Wl[i] = u.v;
    }
    __syncthreads();
    int wave = (blockIdx.x * blockDim.x + threadIdx.x) >> 6;
    int lane = threadIdx.x & 63;
    int ntile = (N + 15) / 16;
    if (wave >= ntile) return;
    int m = lane & 15, quad = lane >> 4;
    int row = wave * 16 + m;
    const short8* Wf = reinterpret_cast<const short8*>(Wl);
    floatx4 acc0 = {0.f, 0.f, 0.f, 0.f}, acc1 = acc0, acc2 = acc0;
    #pragma unroll
    for (int kc = 0; kc < 4; ++kc) {
        const float4* xr = reinterpret_cast<const float4*>(
            x + (size_t)row * N_FEAT + kc * 32 + quad * 8);
        float4 a0 = xr[0], a1 = xr[1];
        short8 af;
        af[0] = f2bf(a0.x); af[1] = f2bf(a0.y); af[2] = f2bf(a0.z); af[3] = f2bf(a0.w);
        af[4] = f2bf(a1.x); af[5] = f2bf(a1.y); af[6] = f2bf(a1.z); af[7] = f2bf(a1.w);
        short8 b0 = Wf[(0 * 4 + kc) * 64 + lane];
        short8 b1 = Wf[(1 * 4 + kc) * 64 + lane];
        short8 b2 = Wf[(2 * 4 + kc) * 64 + lane];
        acc0 = __builtin_amdgcn_mfma_f32_16x16x32_bf16(af, b0, acc0, 0, 0, 0);
        acc1 = __builtin_amdgcn_mfma_f32_16x16x32_bf16(af, b1, acc1, 0, 0, 0);
        acc2 = __builtin_amdgcn_mfma_f32_16x16x32_bf16(af, b2, acc2, 0, 0, 0);
    }
    #pragma unroll
    for (int r = 0; r < 4; ++r) {
        int rw = wave * 16 + quad * 4 + r;
        float ds = dis[rw];
        unsigned short* tr = t0 + (size_t)rw * N_CLASS;
        tr[m] = __half_as_ushort(__float2half(ds * acc0[r]));
        tr[16 + m] = __half_as_ushort(__float2half(ds * acc1[r]));
        if (m < 8) tr[32 + m] = __half_as_ushort(__float2half(ds * acc2[r]));
    }
}

// ---------------------------------------------------------------------------
// Group-per-node gather: 12 groups x 5 lanes per wave; lane sl owns 16 B of
// the 80 B row. f32 accumulation in two banks (A: even edges, B: odd).
struct F8 { float v0, v1, v2, v3, v4, v5, v6, v7; };

__device__ __forceinline__ void acc8(F8& a, uint4 r) {
    float2 f0 = __half22float2(u2h(r.x));
    float2 f1 = __half22float2(u2h(r.y));
    float2 f2 = __half22float2(u2h(r.z));
    float2 f3 = __half22float2(u2h(r.w));
    a.v0 += f0.x; a.v1 += f0.y; a.v2 += f1.x; a.v3 += f1.y;
    a.v4 += f2.x; a.v5 += f2.y; a.v6 += f3.x; a.v7 += f3.y;
}

// Shared gather: group g = lane/5 handles dst d = wave*12+g. Main loop
// unrolled x4 with an int4 srcsB load (alignment prologue: starts[d] is not
// 4-aligned in general). Ghost lanes 60-63 shadow group 11 lane 0.
#define GATHER5(tin)                                                           \
    int wv = (blockIdx.x * blockDim.x + threadIdx.x) >> 6;                     \
    int lane = threadIdx.x & 63;                                               \
    int g = lane / 5;                                                          \
    int sl = lane - g * 5;                                                     \
    if (g > 11) { g = 11; sl = 0; }                                            \
    int d = wv * 12 + g;                                                       \
    int act = (lane < 60) && (d < N);                                          \
    int dc = min(d, N - 1);                                                    \
    int e0 = starts[dc];                                                       \
    int e1 = starts[dc + 1];                                                   \
    if (d >= N) e1 = e0;                                                       \
    int slo = sl << 4;                                                         \
    const char* tbs = (const char*)(tin) + slo;                                \
    F8 A = {0,0,0,0,0,0,0,0}, B = {0,0,0,0,0,0,0,0};                           \
    {                                                                          \
        uint4 rs = *reinterpret_cast<const uint4*>(tbs + (size_t)dc * 80);     \
        acc8(A, rs);                            /* self term row d */          \
    }                                                                          \
    int e = e0;                                                                \
    int ea = min(e1, (e0 + 3) & ~3);                                           \
    for (; e < ea; ++e) {                       /* align to 16 B */            \
        int o = srcsB[e];                                                      \
        uint4 r = *reinterpret_cast<const uint4*>(tbs + (unsigned)o);          \
        acc8(A, r);                                                            \
    }                                                                          \
    for (; e + 4 <= e1; e += 4) {               /* 4 gathers in flight */      \
        int4 o4 = *reinterpret_cast<const int4*>(srcsB + e);                   \
        uint4 r0 = *reinterpret_cast<const uint4*>(tbs + (unsigned)o4.x);      \
        uint4 r1 = *reinterpret_cast<const uint4*>(tbs + (unsigned)o4.y);      \
        uint4 r2 = *reinterpret_cast<const uint4*>(tbs + (unsigned)o4.z);      \
        uint4 r3 = *reinterpret_cast<const uint4*>(tbs + (unsigned)o4.w);      \
        acc8(A, r0); acc8(B, r1); acc8(A, r2); acc8(B, r3);                    \
    }                                                                          \
    for (; e < e1; ++e) {                       /* tail <= 3 edges */          \
        int o = srcsB[e];                                                      \
        uint4 r = *reinterpret_cast<const uint4*>(tbs + (unsigned)o);          \
        acc8(A, r);                                                            \
    }                                                                          \
    A.v0 += B.v0; A.v1 += B.v1; A.v2 += B.v2; A.v3 += B.v3;                    \
    A.v4 += B.v4; A.v5 += B.v5; A.v6 += B.v6; A.v7 += B.v7;

// Middle hop: tout[d] = f16( dd^2 * (t[d] + sum t[src]) )
__global__ __launch_bounds__(256) void prop_hop_kernel(
    const unsigned short* __restrict__ tin, unsigned short* __restrict__ tout,
    const int* __restrict__ starts, const int* __restrict__ srcsB,
    const float* __restrict__ dis, int N)
{
    GATHER5(tin)
    if (act) {
        float dd = dis[dc];
        float sc = dd * dd;
        uint4 o;
        o.x = h2u(__floats2half2_rn(sc * A.v0, sc * A.v1));
        o.y = h2u(__floats2half2_rn(sc * A.v2, sc * A.v3));
        o.z = h2u(__floats2half2_rn(sc * A.v4, sc * A.v5));
        o.w = h2u(__floats2half2_rn(sc * A.v6, sc * A.v7));
        *reinterpret_cast<uint4*>((char*)tout + (size_t)d * 80 + slo) = o;
    }
}

// Final hop fused with bias + log_softmax. Softmax reduce = 4 rotate-shfls
// within the 5-lane group (serves all 12 nodes of the wave at once).
__global__ __launch_bounds__(256) void prop_final_kernel(
    const unsigned short* __restrict__ tin, float* __restrict__ out,
    const int* __restrict__ starts, const int* __restrict__ srcsB,
    const float* __restrict__ dis, const float* __restrict__ bias, int N)
{
    GATHER5(tin)
    float dd = dis[dc];
    float4 blo = reinterpret_cast<const float4*>(bias)[sl * 2];       // sl<5
    float4 bhi = reinterpret_cast<const float4*>(bias)[sl * 2 + 1];
    float v0 = dd * A.v0 + blo.x, v1 = dd * A.v1 + blo.y;
    float v2 = dd * A.v2 + blo.z, v3 = dd * A.v3 + blo.w;
    float v4 = dd * A.v4 + bhi.x, v5 = dd * A.v5 + bhi.y;
    float v6 = dd * A.v6 + bhi.z, v7 = dd * A.v7 + bhi.w;
    float mx = fmaxf(fmaxf(fmaxf(v0, v1), fmaxf(v2, v3)),
                     fmaxf(fmaxf(v4, v5), fmaxf(v6, v7)));
    int rot = g * 5 + ((sl + 1 == 5) ? 0 : sl + 1);     // next lane in group
    float tmx = mx;
    #pragma unroll
    for (int k = 0; k < 4; ++k) { tmx = __shfl(tmx, rot); mx = fmaxf(mx, tmx); }
    float s = expf(v0 - mx) + expf(v1 - mx) + expf(v2 - mx) + expf(v3 - mx)
            + expf(v4 - mx) + expf(v5 - mx) + expf(v6 - mx) + expf(v7 - mx);
    float ts = s;
    #pragma unroll
    for (int k = 0; k < 4; ++k) { ts = __shfl(ts, rot); s += ts; }
    if (act) {
        float ls = mx + logf(s);
        float* ro = out + (size_t)d * N_CLASS + sl * 8;
        *reinterpret_cast<float4*>(ro)     = make_float4(v0 - ls, v1 - ls, v2 - ls, v3 - ls);
        *reinterpret_cast<float4*>(ro + 4) = make_float4(v4 - ls, v5 - ls, v6 - ls, v7 - ls);
    }
}

// ---------------------------------------------------------------------------
extern "C" void kernel_launch(void* const* d_in, const int* in_sizes, int n_in,
                              void* d_out, int out_size, void* d_ws, size_t ws_size,
                              hipStream_t stream) {
    const float* feature = (const float*)d_in[0];   // [N, 128]
    const float* weight  = (const float*)d_in[1];   // [40, 128]
    const float* bias    = (const float*)d_in[2];   // [40]
    const int*   ei      = (const int*)d_in[3];     // [2, E] (int32 or int64 words)
    const int N = N_NODES;
    const int E = in_sizes[3] / 2;

    size_t off = 0;
    auto take = [&](size_t bytes) { size_t o = off; off += (bytes + 255) & ~(size_t)255; return o; };
    char* ws = (char*)d_ws;
    int*   flag      = (int*)  (ws + take(4));
    int*   bCount    = (int*)  (ws + take((size_t)NBALLOC * 4));
    int*   bStart    = (int*)  (ws + take((size_t)(NBALLOC + 1) * 4));
    int*   bCursor   = (int*)  (ws + take((size_t)NBALLOC * 4));
    int*   coarseCnt = (int*)  (ws + take((size_t)NCALLOC * 4));
    int*   starts    = (int*)  (ws + take((size_t)(N + 1) * 4));
    float* dis       = (float*)(ws + take((size_t)N * 4));
    // srcsB region also hosts tmpc (coarse records): tmpc dead before p4 writes srcsB
    size_t srcsBytes = (size_t)E * 4;
    size_t tmpcBytes = (size_t)NCALLOC * CCAP * 4;
    size_t bigBytes = srcsBytes > tmpcBytes ? srcsBytes : tmpcBytes;
    char* bigBase = ws + take(bigBytes);
    int* srcsB = (int*)bigBase;
    unsigned int* tmpc = (unsigned int*)bigBase;
    // t0+t1 (16 MB contiguous) also host tmp (fine records, E*4 = 12.8 MB)
    unsigned short* t0 = (unsigned short*)(ws + take((size_t)N * N_CLASS * 2));
    unsigned short* t1 = (unsigned short*)(ws + take((size_t)N * N_CLASS * 2));
    unsigned int* tmp = (unsigned int*)t0;

    // --- build CSR (two-level bucketed counting sort, pow2 ranges) ---
    detect_zero_kernel<<<1, 512, 0, stream>>>(ei, flag, bCount, coarseCnt);
    p3a_scatter<<<P3AGRID, 256, 0, stream>>>(ei, E, flag, bCount, coarseCnt, tmpc);
    p2_scan<<<1, NBALLOC, 0, stream>>>(bCount, bStart, bCursor, starts, E);
    p3b_scatter<<<NCUSED * 8, 256, 0, stream>>>(tmpc, coarseCnt, bCursor, tmp);
    p4_sort<<<NBUSED, 256, 0, stream>>>(tmp, bStart, starts, dis, srcsB, N);

    // --- transform (MFMA, pre-scaled f16 rows) then 2 hops ---
    const int ntile = (N + 15) / 16;
    const int tblocks = (ntile * 64 + 255) / 256;
    transform_mfma<<<tblocks, 256, 0, stream>>>(feature, weight, dis, t0, N);
    const int nwaves = (N + 11) / 12;                     // 12 nodes per wave
    const int nodeBlocks = (nwaves * 64 + 255) / 256;
    prop_hop_kernel<<<nodeBlocks, 256, 0, stream>>>(t0, t1, starts, srcsB, dis, N);
    prop_final_kernel<<<nodeBlocks, 256, 0, stream>>>(t1, (float*)d_out,
                                                      starts, srcsB, dis, bias, N);
}